// Round 3
// baseline (139.491 us; speedup 1.0000x reference)
//
#include <hip/hip_runtime.h>

typedef _Float16 half8 __attribute__((ext_vector_type(8)));
typedef float f32x4 __attribute__((ext_vector_type(4)));
typedef float f32x16 __attribute__((ext_vector_type(16)));
typedef unsigned int u32x4 __attribute__((ext_vector_type(4)));

#define NPTS 1024
#define NB 8
#define HDIM 512
#define CH 16
#define RT 1056              // 1024 pts + row 1024 = x + zero pad to 33*32

// workspace byte offsets
#define OFF_WBH 0u
#define OFF_WBL (4u*1024u*1024u)
#define OFF_A0H (8u*1024u*1024u)
#define A0SZ    (64u*RT*8u*2u)            // 1,081,344 B per a0 half array
#define OFF_A0L (OFF_A0H + A0SZ)
#define OFF_WLH (OFF_A0L + A0SZ)
#define OFF_WLL (OFF_WLH + 16384u)
#define OFF_FS  (OFF_WLL + 16384u)
#define OFF_PP  (OFF_FS + 65536u)
#define PPSZ    (8u*4u*RT*16u*4u)         // 2,162,688 B  (per-(i,nq) partials)
#define OFF_MU  (OFF_PP + PPSZ)
#define OFF_BX  (OFF_MU + 64u)

__device__ __forceinline__ float elu(float z) { return z > 0.f ? z : expm1f(z); }

// ---------- kPrep ----------
// blocks 0..1023   : Wb -> octet hi/lo halves [i*64+koct][n][8], flat (no LDS), 1 octet/thread
// blocks 1024..1287: a0 rows (4/block): elu(s@Wfirst+b) -> octets [koct][m][8]; f_s
// block 1288       : Wlast -> octets [hoct][ch][8]
__global__ __launch_bounds__(256) void kPrep(const float* __restrict__ s,
    const float* __restrict__ x, const float* __restrict__ Wfirst,
    const float* __restrict__ bfirst, const float* __restrict__ Wb,
    const float* __restrict__ Wlast, const float* __restrict__ Wf,
    const float* __restrict__ bf,
    _Float16* __restrict__ Wbh, _Float16* __restrict__ Wbl,
    _Float16* __restrict__ WlH, _Float16* __restrict__ WlL,
    _Float16* __restrict__ a0h, _Float16* __restrict__ a0l,
    float* __restrict__ f_s) {
  __shared__ __align__(16) float sm[8192];
  int b = blockIdx.x, t = threadIdx.x;
  if (b < 1024) {
    int i = b >> 7, koct = (b >> 1) & 63, n = (b & 1) * 256 + t;
    const float* src = Wb + ((size_t)i * 512 + koct * 8) * 512 + n;
    float v[8];
#pragma unroll
    for (int j = 0; j < 8; ++j) v[j] = src[j * 512];
    union { _Float16 h[8]; u32x4 u; } hu, lu;
#pragma unroll
    for (int j = 0; j < 8; ++j) {
      _Float16 hv = (_Float16)v[j];
      hu.h[j] = hv;
      lu.h[j] = (_Float16)(v[j] - (float)hv);
    }
    size_t o = ((size_t)(i * 64 + koct) * 512 + n) * 8;
    *(u32x4*)(Wbh + o) = hu.u;
    *(u32x4*)(Wbl + o) = lu.u;
  } else if (b < 1288) {
    int rr = t >> 6, tl = t & 63;
    int m = (b - 1024) * 4 + rr;
    float* sv = &sm[rr * 8];
    if (tl < 8) sv[tl] = (m < 1024) ? s[m * 8 + tl] : (m == 1024 ? x[tl] : 0.f);
    __syncthreads();
    size_t o = ((size_t)tl * RT + m) * 8;
    if (m <= 1024) {
      float acc[8];
#pragma unroll
      for (int jj = 0; jj < 8; ++jj) acc[jj] = bfirst[8 * tl + jj];
#pragma unroll
      for (int d = 0; d < 8; ++d) {
        float sd = sv[d];
        f32x4 w0 = *(const f32x4*)&Wfirst[d * 512 + 8 * tl];
        f32x4 w1 = *(const f32x4*)&Wfirst[d * 512 + 8 * tl + 4];
#pragma unroll
        for (int e = 0; e < 4; ++e) { acc[e] += sd * w0[e]; acc[4 + e] += sd * w1[e]; }
      }
      union { _Float16 h[8]; u32x4 u; } hu, lu;
#pragma unroll
      for (int jj = 0; jj < 8; ++jj) {
        float v = elu(acc[jj]);
        _Float16 hv = (_Float16)v;
        hu.h[jj] = hv;
        lu.h[jj] = (_Float16)(v - (float)hv);
      }
      *(u32x4*)(a0h + o) = hu.u;
      *(u32x4*)(a0l + o) = lu.u;
      if (m < 1024 && tl < 16) {
        float a = bf[tl];
#pragma unroll
        for (int d = 0; d < 8; ++d) a += sv[d] * Wf[d * 16 + tl];
        f_s[m * 16 + tl] = a;
      }
    } else {
      u32x4 z;
#pragma unroll
      for (int e = 0; e < 4; ++e) z[e] = 0u;
      *(u32x4*)(a0h + o) = z;
      *(u32x4*)(a0l + o) = z;
    }
  } else {
#pragma unroll
    for (int it = 0; it < 32; ++it) sm[t + 256 * it] = Wlast[t + 256 * it];
    __syncthreads();
#pragma unroll
    for (int p = 0; p < 4; ++p) {
      int oi = p * 256 + t;
      int ko = oi >> 4, ch = oi & 15;
      union { _Float16 h[8]; u32x4 u; } hu, lu;
#pragma unroll
      for (int jj = 0; jj < 8; ++jj) {
        float v = sm[(ko * 8 + jj) * 16 + ch];
        _Float16 hv = (_Float16)v;
        hu.h[jj] = hv;
        lu.h[jj] = (_Float16)(v - (float)hv);
      }
      *(u32x4*)(WlH + oi * 8) = hu.u;
      *(u32x4*)(WlL + oi * 8) = lu.u;
    }
  }
}

// ---------- kB: split-f16 MFMA GEMM, latency-pipelined, no main-loop barriers ----------
// grid 1056 = i(8, ==XCD) x mt(33) x nq(4). Block: 32 m x 128 n; wave: 32 m x 32 n.
// A and B octets read straight from L2 (A shared by all 4 waves -> L1 hits).
// Register double-buffer over macro-iters of K=32 (2 MFMA k-steps).
__global__ __launch_bounds__(256, 3) void kB(const _Float16* __restrict__ Wbh,
    const _Float16* __restrict__ Wbl, const _Float16* __restrict__ a0h,
    const _Float16* __restrict__ a0l, const _Float16* __restrict__ WlH,
    const _Float16* __restrict__ WlL, const float* __restrict__ bb,
    float* __restrict__ Pp) {
  __shared__ u32x4 SC[1024];     // 16 KB epilogue scratch: per wave 128 hi + 128 lo octets
  __shared__ float S2[32][16];
  int t = threadIdx.x, b = blockIdx.x;
  int i = b & 7, r = b >> 3;
  int nq = r & 3, mt = r >> 2;
  int m0 = mt * 32;
  int w = t >> 6, lane = t & 63, ln = lane & 31, q = lane >> 5, q4 = lane >> 4;
  int nw = nq * 128 + w * 32;

  const u32x4* a0h4 = (const u32x4*)a0h;
  const u32x4* a0l4 = (const u32x4*)a0l;
  const u32x4* bh4  = (const u32x4*)Wbh;
  const u32x4* bl4  = (const u32x4*)Wbl;
  int ma = m0 + ln, nb = nw + ln, ib = i * 64;

  f32x16 hh, hl, lh;
#pragma unroll
  for (int rr = 0; rr < 16; ++rr) { hh[rr] = 0.f; hl[rr] = 0.f; lh[rr] = 0.f; }

  u32x4 paH[2][2], paL[2][2], pbH[2][2], pbL[2][2];
  // preload macro 0
  {
    int k0 = q, k1 = q + 2;
    paH[0][0] = a0h4[k0 * RT + ma]; paL[0][0] = a0l4[k0 * RT + ma];
    paH[0][1] = a0h4[k1 * RT + ma]; paL[0][1] = a0l4[k1 * RT + ma];
    pbH[0][0] = bh4[(size_t)(ib + k0) * 512 + nb]; pbL[0][0] = bl4[(size_t)(ib + k0) * 512 + nb];
    pbH[0][1] = bh4[(size_t)(ib + k1) * 512 + nb]; pbL[0][1] = bl4[(size_t)(ib + k1) * 512 + nb];
  }
#pragma unroll
  for (int ks2 = 0; ks2 < 16; ++ks2) {
    int nx = (ks2 < 15) ? ks2 + 1 : 15;       // last prefetch redundant (harmless)
    int bn = (ks2 + 1) & 1, bc = ks2 & 1;
    {
      int k0 = nx * 4 + q, k1 = k0 + 2;
      paH[bn][0] = a0h4[k0 * RT + ma]; paL[bn][0] = a0l4[k0 * RT + ma];
      paH[bn][1] = a0h4[k1 * RT + ma]; paL[bn][1] = a0l4[k1 * RT + ma];
      pbH[bn][0] = bh4[(size_t)(ib + k0) * 512 + nb]; pbL[bn][0] = bl4[(size_t)(ib + k0) * 512 + nb];
      pbH[bn][1] = bh4[(size_t)(ib + k1) * 512 + nb]; pbL[bn][1] = bl4[(size_t)(ib + k1) * 512 + nb];
    }
#pragma unroll
    for (int sfx = 0; sfx < 2; ++sfx) {
      half8 aH = __builtin_bit_cast(half8, paH[bc][sfx]);
      half8 aL = __builtin_bit_cast(half8, paL[bc][sfx]);
      half8 bH = __builtin_bit_cast(half8, pbH[bc][sfx]);
      half8 bL = __builtin_bit_cast(half8, pbL[bc][sfx]);
      hh = __builtin_amdgcn_mfma_f32_32x32x16_f16(aH, bH, hh, 0, 0, 0);
      hl = __builtin_amdgcn_mfma_f32_32x32x16_f16(aH, bL, hl, 0, 0, 0);
      lh = __builtin_amdgcn_mfma_f32_32x32x16_f16(aL, bH, lh, 0, 0, 0);
    }
  }

  // ---- epilogue: bias + elu, re-split to f16 A-frags, project with Wlast ----
  ((float*)S2)[t] = 0.f;
  ((float*)S2)[t + 256] = 0.f;
  float bcol = bb[i * 512 + nw + ln];          // this lane's column bias
  _Float16* scrH = (_Float16*)&SC[w * 256];
  _Float16* scrL = (_Float16*)&SC[w * 256 + 128];
#pragma unroll
  for (int rr = 0; rr < 16; ++rr) {
    int row = (rr & 3) + 8 * (rr >> 2) + 4 * q;      // 32x32 C-layout row
    float a1 = elu(hh[rr] + hl[rr] + lh[rr] + bcol);
    _Float16 hv = (_Float16)a1;
    _Float16 lv = (_Float16)(a1 - (float)hv);
    int oi = (row >> 4) * 64 + (ln >> 3) * 16 + (row & 15);   // [mt2][koct][m16]
    scrH[oi * 8 + (ln & 7)] = hv;
    scrL[oi * 8 + (ln & 7)] = lv;
  }
  __syncthreads();

  const u32x4* sH4 = &SC[w * 256];
  const u32x4* sL4 = &SC[w * 256 + 128];
  const u32x4* wh4 = (const u32x4*)WlH;
  const u32x4* wl4 = (const u32x4*)WlL;
  int ch = lane & 15;
  size_t wo = (size_t)((nw >> 3) + q4) * 16 + ch;
  half8 wH = __builtin_bit_cast(half8, wh4[wo]);
  half8 wL = __builtin_bit_cast(half8, wl4[wo]);
#pragma unroll
  for (int mt2 = 0; mt2 < 2; ++mt2) {
    f32x4 D2;
#pragma unroll
    for (int rr = 0; rr < 4; ++rr) D2[rr] = 0.f;
    int ai = mt2 * 64 + q4 * 16 + ch;
    half8 pH = __builtin_bit_cast(half8, sH4[ai]);
    half8 pL = __builtin_bit_cast(half8, sL4[ai]);
    D2 = __builtin_amdgcn_mfma_f32_16x16x32_f16(pH, wH, D2, 0, 0, 0);
    D2 = __builtin_amdgcn_mfma_f32_16x16x32_f16(pH, wL, D2, 0, 0, 0);
    D2 = __builtin_amdgcn_mfma_f32_16x16x32_f16(pL, wH, D2, 0, 0, 0);
#pragma unroll
    for (int rr = 0; rr < 4; ++rr)
      atomicAdd(&S2[mt2 * 16 + q4 * 4 + rr][ch], D2[rr]);
  }
  __syncthreads();
  for (int o = t; o < 512; o += 256) {
    int m = o >> 4, c2 = o & 15;
    Pp[((size_t)(i * 4 + nq) * RT + m0 + m) * 16 + c2] = S2[m][c2];
  }
}

// ---------- kTail: per-basis diff^2 reduction -> mu, plus basisx ----------
__global__ __launch_bounds__(256) void kTail(const float* __restrict__ Pp,
    const float* __restrict__ f_s, const float* __restrict__ blast,
    float* __restrict__ mu, float* __restrict__ basisx) {
  __shared__ float R[16][16];
  __shared__ float sc[16];
  int i = blockIdx.x, t = threadIdx.x, ch = t & 15, g = t >> 4;
  const float* P0 = Pp + (size_t)(i * 4) * RT * 16;
  const size_t PS = (size_t)RT * 16;
  float bl = blast[ch];
  float loc = 0.f;
#pragma unroll 4
  for (int it = 0; it < 64; ++it) {
    int m = g + 16 * it;
    size_t o = (size_t)m * 16 + ch;
    float bs = P0[o] + P0[PS + o] + P0[2 * PS + o] + P0[3 * PS + o] + bl;
    float d = f_s[o] - bs;
    loc += d * d;
  }
  R[g][ch] = loc;
  if (t < 16) {
    size_t o = (size_t)1024 * 16 + t;
    basisx[i * 16 + t] = P0[o] + P0[PS + o] + P0[2 * PS + o] + P0[3 * PS + o] + blast[t];
  }
  __syncthreads();
  if (t < 16) {
    float s2 = 0.f;
#pragma unroll
    for (int gg = 0; gg < 16; ++gg) s2 += R[gg][t];
    sc[t] = s2;
  }
  __syncthreads();
  if (t == 0) {
    float S = 0.f;
#pragma unroll
    for (int c = 0; c < 16; ++c) S += sc[c];
    float nb = 0.5f * sqrtf(S);   // sqrt(VOLUME/NPTS * S) = sqrt(S/4)
    mu[i] = (nb <= 1000.0f) ? nb : 0.f;
  }
}

// ---------- kFin: weighted combine ----------
__global__ __launch_bounds__(128) void kFin(const float* __restrict__ mu,
    const float* __restrict__ basisx, float* __restrict__ out) {
  __shared__ float muL[8];
  int t = threadIdx.x;
  if (t < 8) muL[t] = mu[t];
  __syncthreads();
  int ch = t & 15;
  float num = 0.f, den = 1e-7f;
#pragma unroll
  for (int i = 0; i < NB; ++i) {
    num += muL[i] * basisx[i * 16 + ch];
    den += muL[i];
  }
  out[t] = num / den;
}

extern "C" void kernel_launch(void* const* d_in, const int* in_sizes, int n_in,
                              void* d_out, int out_size, void* d_ws, size_t ws_size,
                              hipStream_t stream) {
  const float* s      = (const float*)d_in[0];
  const float* x      = (const float*)d_in[1];
  const float* Wfirst = (const float*)d_in[2];
  const float* bfirst = (const float*)d_in[3];
  const float* Wb     = (const float*)d_in[4];
  const float* bb     = (const float*)d_in[5];
  const float* Wlast  = (const float*)d_in[6];
  const float* blast  = (const float*)d_in[7];
  const float* Wf     = (const float*)d_in[8];
  const float* bf     = (const float*)d_in[9];

  char* ws = (char*)d_ws;
  _Float16* Wbh = (_Float16*)(ws + OFF_WBH);
  _Float16* Wbl = (_Float16*)(ws + OFF_WBL);
  _Float16* a0h = (_Float16*)(ws + OFF_A0H);
  _Float16* a0l = (_Float16*)(ws + OFF_A0L);
  _Float16* WlH = (_Float16*)(ws + OFF_WLH);
  _Float16* WlL = (_Float16*)(ws + OFF_WLL);
  float* f_s    = (float*)(ws + OFF_FS);
  float* Pp     = (float*)(ws + OFF_PP);
  float* mu     = (float*)(ws + OFF_MU);
  float* basisx = (float*)(ws + OFF_BX);
  float* out    = (float*)d_out;

  kPrep<<<1289, 256, 0, stream>>>(s, x, Wfirst, bfirst, Wb, Wlast, Wf, bf,
                                  Wbh, Wbl, WlH, WlL, a0h, a0l, f_s);
  kB<<<1056, 256, 0, stream>>>(Wbh, Wbl, a0h, a0l, WlH, WlL, bb, Pp);
  kTail<<<NB, 256, 0, stream>>>(Pp, f_s, blast, mu, basisx);
  kFin<<<1, 128, 0, stream>>>(mu, basisx, out);
}

// Round 4
// 116.864 us; speedup vs baseline: 1.1936x; 1.1936x over previous
//
#include <hip/hip_runtime.h>

typedef _Float16 half8 __attribute__((ext_vector_type(8)));
typedef float f32x4 __attribute__((ext_vector_type(4)));
typedef float f32x16 __attribute__((ext_vector_type(16)));
typedef unsigned int u32x4 __attribute__((ext_vector_type(4)));

#define NPTS 1024
#define NB 8
#define HDIM 512
#define CH 16
#define RT 1056              // 1024 pts + row 1024 = x + zero pad to 33*32

// workspace byte offsets
#define OFF_WBF 0u                         // 8*64*512*16B = 4 MB
#define OFF_A0F (4u*1024u*1024u)
#define A0SZ    (64u*RT*16u)               // 1,081,344
#define OFF_WLF (OFF_A0F + A0SZ)
#define OFF_FS  (OFF_WLF + 16384u)
#define OFF_PP  (OFF_FS + 65536u)
#define PPSZ    (8u*4u*RT*16u*4u)          // 2,162,688
#define OFF_MU  (OFF_PP + PPSZ)
#define OFF_BX  (OFF_MU + 64u)

__device__ __forceinline__ float elu(float z) { return z > 0.f ? z : expm1f(z); }

// ---------- kPrep ----------
// blocks 0..1023   : Wb -> f16 octets [i*64+koct][n][8], 1 octet/thread
// blocks 1024..1287: a0 rows (4/block): elu(s@Wfirst+b) -> octets [koct][m][8]; f_s
// block 1288       : Wlast -> octets [hoct][ch][8]
__global__ __launch_bounds__(256) void kPrep(const float* __restrict__ s,
    const float* __restrict__ x, const float* __restrict__ Wfirst,
    const float* __restrict__ bfirst, const float* __restrict__ Wb,
    const float* __restrict__ Wlast, const float* __restrict__ Wf,
    const float* __restrict__ bf,
    _Float16* __restrict__ Wbf, _Float16* __restrict__ Wlf,
    _Float16* __restrict__ a0f, float* __restrict__ f_s) {
  __shared__ __align__(16) float sm[8192];
  int b = blockIdx.x, t = threadIdx.x;
  if (b < 1024) {
    int i = b >> 7, koct = (b >> 1) & 63, n = (b & 1) * 256 + t;
    const float* src = Wb + ((size_t)i * 512 + koct * 8) * 512 + n;
    float v[8];
#pragma unroll
    for (int j = 0; j < 8; ++j) v[j] = src[j * 512];
    union { _Float16 h[8]; u32x4 u; } hu;
#pragma unroll
    for (int j = 0; j < 8; ++j) hu.h[j] = (_Float16)v[j];
    *(u32x4*)(Wbf + ((size_t)(i * 64 + koct) * 512 + n) * 8) = hu.u;
  } else if (b < 1288) {
    int rr = t >> 6, tl = t & 63;
    int m = (b - 1024) * 4 + rr;
    float* sv = &sm[rr * 8];
    if (tl < 8) sv[tl] = (m < 1024) ? s[m * 8 + tl] : (m == 1024 ? x[tl] : 0.f);
    __syncthreads();
    size_t o = ((size_t)tl * RT + m) * 8;
    if (m <= 1024) {
      float acc[8];
#pragma unroll
      for (int jj = 0; jj < 8; ++jj) acc[jj] = bfirst[8 * tl + jj];
#pragma unroll
      for (int d = 0; d < 8; ++d) {
        float sd = sv[d];
        f32x4 w0 = *(const f32x4*)&Wfirst[d * 512 + 8 * tl];
        f32x4 w1 = *(const f32x4*)&Wfirst[d * 512 + 8 * tl + 4];
#pragma unroll
        for (int e = 0; e < 4; ++e) { acc[e] += sd * w0[e]; acc[4 + e] += sd * w1[e]; }
      }
      union { _Float16 h[8]; u32x4 u; } hu;
#pragma unroll
      for (int jj = 0; jj < 8; ++jj) hu.h[jj] = (_Float16)elu(acc[jj]);
      *(u32x4*)(a0f + o) = hu.u;
      if (m < 1024 && tl < 16) {
        float a = bf[tl];
#pragma unroll
        for (int d = 0; d < 8; ++d) a += sv[d] * Wf[d * 16 + tl];
        f_s[m * 16 + tl] = a;
      }
    } else {
      u32x4 z;
#pragma unroll
      for (int e = 0; e < 4; ++e) z[e] = 0u;
      *(u32x4*)(a0f + o) = z;
    }
  } else {
#pragma unroll
    for (int it = 0; it < 32; ++it) sm[t + 256 * it] = Wlast[t + 256 * it];
    __syncthreads();
#pragma unroll
    for (int p = 0; p < 4; ++p) {
      int oi = p * 256 + t;
      int ko = oi >> 4, ch = oi & 15;
      union { _Float16 h[8]; u32x4 u; } hu;
#pragma unroll
      for (int jj = 0; jj < 8; ++jj) hu.h[jj] = (_Float16)sm[(ko * 8 + jj) * 16 + ch];
      *(u32x4*)(Wlf + oi * 8) = hu.u;
    }
  }
}

// ---------- kB: single-f16 MFMA GEMM, 4-deep register pipeline, no main-loop barriers ----------
// grid 1056 = i(8, ==XCD) x mt(33) x nq(4). Block: 32m x 128n; wave: 32m x 32n.
// A/B octets straight from L1/L2. Macro-iter = K=32 (2 MFMA k-steps); prefetch distance 3.
__global__ __launch_bounds__(256, 4) void kB(const _Float16* __restrict__ Wbf,
    const _Float16* __restrict__ a0f, const _Float16* __restrict__ Wlf,
    const float* __restrict__ bb, float* __restrict__ Pp) {
  __shared__ u32x4 SC[512];      // 8 KB: per-wave 128 a1 octets (A-frag layout)
  __shared__ float S2[32][16];
  int t = threadIdx.x, b = blockIdx.x;
  int i = b & 7, r = b >> 3;
  int nq = r & 3, mt = r >> 2;
  int m0 = mt * 32;
  int w = t >> 6, lane = t & 63, ln = lane & 31, q = lane >> 5, q4 = lane >> 4;
  int nw = nq * 128 + w * 32;

  const u32x4* a4 = (const u32x4*)a0f;
  const u32x4* b4 = (const u32x4*)Wbf;
  int ma = m0 + ln, nb = nw + ln, ib = i * 64;

  f32x16 acc;
#pragma unroll
  for (int rr = 0; rr < 16; ++rr) acc[rr] = 0.f;

  u32x4 pa[4][2], pb[4][2];
#pragma unroll
  for (int st = 0; st < 3; ++st) {
    int k0 = st * 4 + q, k1 = k0 + 2;
    pa[st][0] = a4[k0 * RT + ma];
    pa[st][1] = a4[k1 * RT + ma];
    pb[st][0] = b4[(size_t)(ib + k0) * 512 + nb];
    pb[st][1] = b4[(size_t)(ib + k1) * 512 + nb];
  }
#pragma unroll
  for (int ks = 0; ks < 16; ++ks) {
    int sl = ks & 3;
    acc = __builtin_amdgcn_mfma_f32_32x32x16_f16(
        __builtin_bit_cast(half8, pa[sl][0]), __builtin_bit_cast(half8, pb[sl][0]), acc, 0, 0, 0);
    acc = __builtin_amdgcn_mfma_f32_32x32x16_f16(
        __builtin_bit_cast(half8, pa[sl][1]), __builtin_bit_cast(half8, pb[sl][1]), acc, 0, 0, 0);
    if (ks < 13) {
      int sn = (ks + 3) & 3;
      int k0 = (ks + 3) * 4 + q, k1 = k0 + 2;
      pa[sn][0] = a4[k0 * RT + ma];
      pa[sn][1] = a4[k1 * RT + ma];
      pb[sn][0] = b4[(size_t)(ib + k0) * 512 + nb];
      pb[sn][1] = b4[(size_t)(ib + k1) * 512 + nb];
    }
  }

  // ---- epilogue: bias + elu -> f16 A-frags (per-wave LDS scratch), project with Wlast ----
  ((float*)S2)[t] = 0.f;
  ((float*)S2)[t + 256] = 0.f;
  float bcol = bb[i * 512 + nw + ln];
  _Float16* scr = (_Float16*)&SC[w * 128];
#pragma unroll
  for (int rr = 0; rr < 16; ++rr) {
    int row = (rr & 3) + 8 * (rr >> 2) + 4 * q;               // 32x32 C-layout row
    float a1 = elu(acc[rr] + bcol);
    int oi = (row >> 4) * 64 + (ln >> 3) * 16 + (row & 15);   // [mt2][koct][m16]
    scr[oi * 8 + (ln & 7)] = (_Float16)a1;
  }
  __syncthreads();

  const u32x4* s4 = &SC[w * 128];
  const u32x4* w4 = (const u32x4*)Wlf;
  int ch = lane & 15;
  half8 wv = __builtin_bit_cast(half8, w4[(size_t)((nw >> 3) + q4) * 16 + ch]);
#pragma unroll
  for (int mt2 = 0; mt2 < 2; ++mt2) {
    f32x4 D2;
#pragma unroll
    for (int rr = 0; rr < 4; ++rr) D2[rr] = 0.f;
    half8 pv = __builtin_bit_cast(half8, s4[mt2 * 64 + q4 * 16 + ch]);
    D2 = __builtin_amdgcn_mfma_f32_16x16x32_f16(pv, wv, D2, 0, 0, 0);
#pragma unroll
    for (int rr = 0; rr < 4; ++rr)
      atomicAdd(&S2[mt2 * 16 + q4 * 4 + rr][ch], D2[rr]);
  }
  __syncthreads();
  for (int o = t; o < 512; o += 256) {
    int m = o >> 4, c2 = o & 15;
    Pp[((size_t)(i * 4 + nq) * RT + m0 + m) * 16 + c2] = S2[m][c2];
  }
}

// ---------- kTail: per-basis diff^2 reduction -> mu, plus basisx ----------
__global__ __launch_bounds__(256) void kTail(const float* __restrict__ Pp,
    const float* __restrict__ f_s, const float* __restrict__ blast,
    float* __restrict__ mu, float* __restrict__ basisx) {
  __shared__ float R[16][16];
  __shared__ float sc[16];
  int i = blockIdx.x, t = threadIdx.x, ch = t & 15, g = t >> 4;
  const float* P0 = Pp + (size_t)(i * 4) * RT * 16;
  const size_t PS = (size_t)RT * 16;
  float bl = blast[ch];
  float loc = 0.f;
#pragma unroll 4
  for (int it = 0; it < 64; ++it) {
    int m = g + 16 * it;
    size_t o = (size_t)m * 16 + ch;
    float bs = P0[o] + P0[PS + o] + P0[2 * PS + o] + P0[3 * PS + o] + bl;
    float d = f_s[o] - bs;
    loc += d * d;
  }
  R[g][ch] = loc;
  if (t < 16) {
    size_t o = (size_t)1024 * 16 + t;
    basisx[i * 16 + t] = P0[o] + P0[PS + o] + P0[2 * PS + o] + P0[3 * PS + o] + blast[t];
  }
  __syncthreads();
  if (t < 16) {
    float s2 = 0.f;
#pragma unroll
    for (int gg = 0; gg < 16; ++gg) s2 += R[gg][t];
    sc[t] = s2;
  }
  __syncthreads();
  if (t == 0) {
    float S = 0.f;
#pragma unroll
    for (int c = 0; c < 16; ++c) S += sc[c];
    float nb = 0.5f * sqrtf(S);   // sqrt(VOLUME/NPTS * S) = sqrt(S/4)
    mu[i] = (nb <= 1000.0f) ? nb : 0.f;
  }
}

// ---------- kFin: weighted combine ----------
__global__ __launch_bounds__(128) void kFin(const float* __restrict__ mu,
    const float* __restrict__ basisx, float* __restrict__ out) {
  __shared__ float muL[8];
  int t = threadIdx.x;
  if (t < 8) muL[t] = mu[t];
  __syncthreads();
  int ch = t & 15;
  float num = 0.f, den = 1e-7f;
#pragma unroll
  for (int i = 0; i < NB; ++i) {
    num += muL[i] * basisx[i * 16 + ch];
    den += muL[i];
  }
  out[t] = num / den;
}

extern "C" void kernel_launch(void* const* d_in, const int* in_sizes, int n_in,
                              void* d_out, int out_size, void* d_ws, size_t ws_size,
                              hipStream_t stream) {
  const float* s      = (const float*)d_in[0];
  const float* x      = (const float*)d_in[1];
  const float* Wfirst = (const float*)d_in[2];
  const float* bfirst = (const float*)d_in[3];
  const float* Wb     = (const float*)d_in[4];
  const float* bb     = (const float*)d_in[5];
  const float* Wlast  = (const float*)d_in[6];
  const float* blast  = (const float*)d_in[7];
  const float* Wf     = (const float*)d_in[8];
  const float* bf     = (const float*)d_in[9];

  char* ws = (char*)d_ws;
  _Float16* Wbf = (_Float16*)(ws + OFF_WBF);
  _Float16* a0f = (_Float16*)(ws + OFF_A0F);
  _Float16* Wlf = (_Float16*)(ws + OFF_WLF);
  float* f_s    = (float*)(ws + OFF_FS);
  float* Pp     = (float*)(ws + OFF_PP);
  float* mu     = (float*)(ws + OFF_MU);
  float* basisx = (float*)(ws + OFF_BX);
  float* out    = (float*)d_out;

  kPrep<<<1289, 256, 0, stream>>>(s, x, Wfirst, bfirst, Wb, Wlast, Wf, bf,
                                  Wbf, Wlf, a0f, f_s);
  kB<<<1056, 256, 0, stream>>>(Wbf, a0f, Wlf, bb, Pp);
  kTail<<<NB, 256, 0, stream>>>(Pp, f_s, blast, mu, basisx);
  kFin<<<1, 128, 0, stream>>>(mu, basisx, out);
}

// Round 5
// 116.170 us; speedup vs baseline: 1.2007x; 1.0060x over previous
//
#include <hip/hip_runtime.h>

typedef _Float16 half8 __attribute__((ext_vector_type(8)));
typedef float f32x4 __attribute__((ext_vector_type(4)));
typedef float f32x16 __attribute__((ext_vector_type(16)));
typedef unsigned int u32x4 __attribute__((ext_vector_type(4)));

#define NPTS 1024
#define NB 8
#define HDIM 512
#define CH 16
#define RT 1056              // 1024 pts + row 1024 = x + zero pad to 33*32

// workspace byte offsets
#define OFF_WBF 0u                         // 8*64*512*16B = 4 MB
#define OFF_A0F (4u*1024u*1024u)
#define A0SZ    (64u*RT*16u)               // 1,081,344
#define OFF_WLF (OFF_A0F + A0SZ)
#define OFF_FS  (OFF_WLF + 16384u)
#define OFF_PP  (OFF_FS + 65536u)
#define PPSZ    (8u*4u*RT*16u*4u)          // 2,162,688
#define OFF_IS  (OFF_PP + PPSZ)
#define OFF_BX  (OFF_IS + 64u)

__device__ __forceinline__ float elu(float z) { return z > 0.f ? z : expm1f(z); }

// ---------- kPrep ----------
// blocks 0..1023   : Wb -> f16 octets [i*64+koct][n][8], 1 octet/thread
// blocks 1024..1287: a0 rows (4/block): elu(s@Wfirst+b) -> octets [koct][m][8]; f_s
// block 1288       : Wlast -> octets [hoct][ch][8]; zero Isum
__global__ __launch_bounds__(256) void kPrep(const float* __restrict__ s,
    const float* __restrict__ x, const float* __restrict__ Wfirst,
    const float* __restrict__ bfirst, const float* __restrict__ Wb,
    const float* __restrict__ Wlast, const float* __restrict__ Wf,
    const float* __restrict__ bf,
    _Float16* __restrict__ Wbf, _Float16* __restrict__ Wlf,
    _Float16* __restrict__ a0f, float* __restrict__ f_s,
    float* __restrict__ Isum) {
  __shared__ __align__(16) float sm[8192];
  int b = blockIdx.x, t = threadIdx.x;
  if (b < 1024) {
    int i = b >> 7, koct = (b >> 1) & 63, n = (b & 1) * 256 + t;
    const float* src = Wb + ((size_t)i * 512 + koct * 8) * 512 + n;
    float v[8];
#pragma unroll
    for (int j = 0; j < 8; ++j) v[j] = src[j * 512];
    union { _Float16 h[8]; u32x4 u; } hu;
#pragma unroll
    for (int j = 0; j < 8; ++j) hu.h[j] = (_Float16)v[j];
    *(u32x4*)(Wbf + ((size_t)(i * 64 + koct) * 512 + n) * 8) = hu.u;
  } else if (b < 1288) {
    int rr = t >> 6, tl = t & 63;
    int m = (b - 1024) * 4 + rr;
    float* sv = &sm[rr * 8];
    if (tl < 8) sv[tl] = (m < 1024) ? s[m * 8 + tl] : (m == 1024 ? x[tl] : 0.f);
    __syncthreads();
    size_t o = ((size_t)tl * RT + m) * 8;
    if (m <= 1024) {
      float acc[8];
#pragma unroll
      for (int jj = 0; jj < 8; ++jj) acc[jj] = bfirst[8 * tl + jj];
#pragma unroll
      for (int d = 0; d < 8; ++d) {
        float sd = sv[d];
        f32x4 w0 = *(const f32x4*)&Wfirst[d * 512 + 8 * tl];
        f32x4 w1 = *(const f32x4*)&Wfirst[d * 512 + 8 * tl + 4];
#pragma unroll
        for (int e = 0; e < 4; ++e) { acc[e] += sd * w0[e]; acc[4 + e] += sd * w1[e]; }
      }
      union { _Float16 h[8]; u32x4 u; } hu;
#pragma unroll
      for (int jj = 0; jj < 8; ++jj) hu.h[jj] = (_Float16)elu(acc[jj]);
      *(u32x4*)(a0f + o) = hu.u;
      if (m < 1024 && tl < 16) {
        float a = bf[tl];
#pragma unroll
        for (int d = 0; d < 8; ++d) a += sv[d] * Wf[d * 16 + tl];
        f_s[m * 16 + tl] = a;
      }
    } else {
      u32x4 z;
#pragma unroll
      for (int e = 0; e < 4; ++e) z[e] = 0u;
      *(u32x4*)(a0f + o) = z;
    }
  } else {
    if (t < 8) Isum[t] = 0.f;
#pragma unroll
    for (int it = 0; it < 32; ++it) sm[t + 256 * it] = Wlast[t + 256 * it];
    __syncthreads();
#pragma unroll
    for (int p = 0; p < 4; ++p) {
      int oi = p * 256 + t;
      int ko = oi >> 4, ch = oi & 15;
      union { _Float16 h[8]; u32x4 u; } hu;
#pragma unroll
      for (int jj = 0; jj < 8; ++jj) hu.h[jj] = (_Float16)sm[(ko * 8 + jj) * 16 + ch];
      *(u32x4*)(Wlf + oi * 8) = hu.u;
    }
  }
}

// ---------- kB: single-f16 MFMA GEMM, 4-deep register pipeline, no main-loop barriers ----------
// grid 1056 = i(8, ==XCD) x mt(33) x nq(4). Block: 32m x 128n; wave: 32m x 32n.
// A/B octets straight from L1/L2. Macro-iter = K=32 (2 MFMA k-steps); prefetch distance 3.
__global__ __launch_bounds__(256, 4) void kB(const _Float16* __restrict__ Wbf,
    const _Float16* __restrict__ a0f, const _Float16* __restrict__ Wlf,
    const float* __restrict__ bb, float* __restrict__ Pp) {
  __shared__ u32x4 SC[512];      // 8 KB: per-wave 128 a1 octets (A-frag layout)
  __shared__ float S2[32][16];
  int t = threadIdx.x, b = blockIdx.x;
  int i = b & 7, r = b >> 3;
  int nq = r & 3, mt = r >> 2;
  int m0 = mt * 32;
  int w = t >> 6, lane = t & 63, ln = lane & 31, q = lane >> 5, q4 = lane >> 4;
  int nw = nq * 128 + w * 32;

  const u32x4* a4 = (const u32x4*)a0f;
  const u32x4* b4 = (const u32x4*)Wbf;
  int ma = m0 + ln, nb = nw + ln, ib = i * 64;

  f32x16 acc;
#pragma unroll
  for (int rr = 0; rr < 16; ++rr) acc[rr] = 0.f;

  u32x4 pa[4][2], pb[4][2];
#pragma unroll
  for (int st = 0; st < 3; ++st) {
    int k0 = st * 4 + q, k1 = k0 + 2;
    pa[st][0] = a4[k0 * RT + ma];
    pa[st][1] = a4[k1 * RT + ma];
    pb[st][0] = b4[(size_t)(ib + k0) * 512 + nb];
    pb[st][1] = b4[(size_t)(ib + k1) * 512 + nb];
  }
#pragma unroll
  for (int ks = 0; ks < 16; ++ks) {
    int sl = ks & 3;
    acc = __builtin_amdgcn_mfma_f32_32x32x16_f16(
        __builtin_bit_cast(half8, pa[sl][0]), __builtin_bit_cast(half8, pb[sl][0]), acc, 0, 0, 0);
    acc = __builtin_amdgcn_mfma_f32_32x32x16_f16(
        __builtin_bit_cast(half8, pa[sl][1]), __builtin_bit_cast(half8, pb[sl][1]), acc, 0, 0, 0);
    if (ks < 13) {
      int sn = (ks + 3) & 3;
      int k0 = (ks + 3) * 4 + q, k1 = k0 + 2;
      pa[sn][0] = a4[k0 * RT + ma];
      pa[sn][1] = a4[k1 * RT + ma];
      pb[sn][0] = b4[(size_t)(ib + k0) * 512 + nb];
      pb[sn][1] = b4[(size_t)(ib + k1) * 512 + nb];
    }
  }

  // ---- epilogue: bias + elu -> f16 A-frags (per-wave LDS scratch), project with Wlast ----
  ((float*)S2)[t] = 0.f;
  ((float*)S2)[t + 256] = 0.f;
  float bcol = bb[i * 512 + nw + ln];
  _Float16* scr = (_Float16*)&SC[w * 128];
#pragma unroll
  for (int rr = 0; rr < 16; ++rr) {
    int row = (rr & 3) + 8 * (rr >> 2) + 4 * q;               // 32x32 C-layout row
    float a1 = elu(acc[rr] + bcol);
    int oi = (row >> 4) * 64 + (ln >> 3) * 16 + (row & 15);   // [mt2][koct][m16]
    scr[oi * 8 + (ln & 7)] = (_Float16)a1;
  }
  __syncthreads();

  const u32x4* s4 = &SC[w * 128];
  const u32x4* w4 = (const u32x4*)Wlf;
  int ch = lane & 15;
  half8 wv = __builtin_bit_cast(half8, w4[(size_t)((nw >> 3) + q4) * 16 + ch]);
#pragma unroll
  for (int mt2 = 0; mt2 < 2; ++mt2) {
    f32x4 D2;
#pragma unroll
    for (int rr = 0; rr < 4; ++rr) D2[rr] = 0.f;
    half8 pv = __builtin_bit_cast(half8, s4[mt2 * 64 + q4 * 16 + ch]);
    D2 = __builtin_amdgcn_mfma_f32_16x16x32_f16(pv, wv, D2, 0, 0, 0);
#pragma unroll
    for (int rr = 0; rr < 4; ++rr)
      atomicAdd(&S2[mt2 * 16 + q4 * 4 + rr][ch], D2[rr]);
  }
  __syncthreads();
  for (int o = t; o < 512; o += 256) {
    int m = o >> 4, c2 = o & 15;
    Pp[((size_t)(i * 4 + nq) * RT + m0 + m) * 16 + c2] = S2[m][c2];
  }
}

// ---------- kRed: parallel diff^2 reduction -> Isum[i] atomics; basisx from x-row ----------
// grid 264 = i(8) x mt(33). mt<32: 32m x 16ch diff^2 -> one atomicAdd. mt==32: basisx.
__global__ __launch_bounds__(256) void kRed(const float* __restrict__ Pp,
    const float* __restrict__ f_s, const float* __restrict__ blast,
    float* __restrict__ Isum, float* __restrict__ basisx) {
  __shared__ float wsum[4];
  int b = blockIdx.x, t = threadIdx.x;
  int i = b / 33, mt = b - i * 33;
  const float* P0 = Pp + (size_t)(i * 4) * RT * 16;
  const size_t PS = (size_t)RT * 16;
  if (mt == 32) {
    if (t < 16) {
      size_t o = (size_t)1024 * 16 + t;
      basisx[i * 16 + t] = P0[o] + P0[PS + o] + P0[2 * PS + o] + P0[3 * PS + o] + blast[t];
    }
    return;
  }
  float loc = 0.f;
#pragma unroll
  for (int p = 0; p < 2; ++p) {
    int item = t + p * 256;
    int m = mt * 32 + (item >> 4), ch = item & 15;
    size_t o = (size_t)m * 16 + ch;
    float bs = P0[o] + P0[PS + o] + P0[2 * PS + o] + P0[3 * PS + o] + blast[ch];
    float d = f_s[o] - bs;
    loc += d * d;
  }
  loc += __shfl_xor(loc, 1, 64);
  loc += __shfl_xor(loc, 2, 64);
  loc += __shfl_xor(loc, 4, 64);
  loc += __shfl_xor(loc, 8, 64);
  loc += __shfl_xor(loc, 16, 64);
  loc += __shfl_xor(loc, 32, 64);
  int lane = t & 63, w = t >> 6;
  if (lane == 0) wsum[w] = loc;
  __syncthreads();
  if (t == 0) atomicAdd(&Isum[i], wsum[0] + wsum[1] + wsum[2] + wsum[3]);
}

// ---------- kFin: mu from Isum + weighted combine ----------
__global__ __launch_bounds__(128) void kFin(const float* __restrict__ Isum,
    const float* __restrict__ basisx, float* __restrict__ out) {
  __shared__ float muL[8];
  int t = threadIdx.x;
  if (t < 8) {
    float nb = 0.5f * sqrtf(Isum[t]);   // sqrt(VOLUME/NPTS * S) = sqrt(S/4)
    muL[t] = (nb <= 1000.0f) ? nb : 0.f;
  }
  __syncthreads();
  int ch = t & 15;
  float num = 0.f, den = 1e-7f;
#pragma unroll
  for (int i = 0; i < NB; ++i) {
    num += muL[i] * basisx[i * 16 + ch];
    den += muL[i];
  }
  out[t] = num / den;
}

extern "C" void kernel_launch(void* const* d_in, const int* in_sizes, int n_in,
                              void* d_out, int out_size, void* d_ws, size_t ws_size,
                              hipStream_t stream) {
  const float* s      = (const float*)d_in[0];
  const float* x      = (const float*)d_in[1];
  const float* Wfirst = (const float*)d_in[2];
  const float* bfirst = (const float*)d_in[3];
  const float* Wb     = (const float*)d_in[4];
  const float* bb     = (const float*)d_in[5];
  const float* Wlast  = (const float*)d_in[6];
  const float* blast  = (const float*)d_in[7];
  const float* Wf     = (const float*)d_in[8];
  const float* bf     = (const float*)d_in[9];

  char* ws = (char*)d_ws;
  _Float16* Wbf = (_Float16*)(ws + OFF_WBF);
  _Float16* a0f = (_Float16*)(ws + OFF_A0F);
  _Float16* Wlf = (_Float16*)(ws + OFF_WLF);
  float* f_s    = (float*)(ws + OFF_FS);
  float* Pp     = (float*)(ws + OFF_PP);
  float* Isum   = (float*)(ws + OFF_IS);
  float* basisx = (float*)(ws + OFF_BX);
  float* out    = (float*)d_out;

  kPrep<<<1289, 256, 0, stream>>>(s, x, Wfirst, bfirst, Wb, Wlast, Wf, bf,
                                  Wbf, Wlf, a0f, f_s, Isum);
  kB<<<1056, 256, 0, stream>>>(Wbf, a0f, Wlf, bb, Pp);
  kRed<<<264, 256, 0, stream>>>(Pp, f_s, blast, Isum, basisx);
  kFin<<<1, 128, 0, stream>>>(Isum, basisx, out);
}